// Round 9
// baseline (284.633 us; speedup 1.0000x reference)
//
#include <hip/hip_runtime.h>
#include <math.h>

#define T_DIM 2048
#define C_DIM 1024
#define H_NUM 16
#define HD_DIM 64
#define K_LCP 8
#define NEG_VAL -1.0e9f
#define SYNC_MAGIC 0x13579BDF

typedef __bf16 bf16;
typedef __bf16 bf16x4 __attribute__((ext_vector_type(4)));
typedef __bf16 bf16x8 __attribute__((ext_vector_type(8)));
typedef float f32x4 __attribute__((ext_vector_type(4)));

struct Args {
  const float *x, *cosT, *sinT, *Wq, *Wk, *Wv, *Wproj, *Wdq, *Wdk;
  float* out;
  bf16 *xb, *wqt, *wkt, *wvt, *wpt, *qB, *kB, *vB;
  float *qd, *kd, *vtsum, *vmean, *partial, *rowout;
  int *tilemask, *allmask, *qneed, *kneed, *vneed, *vtneed, *pneed;
  int* sync;  // [0]=init flag, [1]=count, [2]=generation
};

union SmemU {
  struct {
    float qs[16][64]; float qds[16][8]; float ks[64][64]; float vs[64][64];
    float kds[64][8]; float sc[16][68];
  } attn;                                    // 43776 B (max member)
  struct { bf16 As[128 * 32]; bf16 Bs[128 * 32]; } gemm;
  struct { bf16 tile[64][65]; } tp;
  struct { float xm[C_DIM]; float red[4][64]; } mv;
  struct { float qds[16][8]; int tm[32]; } tmask;
};

// ---- software grid barrier (all 256 blocks co-resident: 1 block/CU) -----------
__device__ void gsync(int* s, int nb) {
  __syncthreads();
  if (threadIdx.x == 0) {
    __threadfence();  // release: make prior writes agent-visible
    int g = __hip_atomic_load(&s[2], __ATOMIC_RELAXED, __HIP_MEMORY_SCOPE_AGENT);
    int old = __hip_atomic_fetch_add(&s[1], 1, __ATOMIC_ACQ_REL,
                                     __HIP_MEMORY_SCOPE_AGENT);
    if (old == nb - 1) {
      __hip_atomic_store(&s[1], 0, __ATOMIC_RELAXED, __HIP_MEMORY_SCOPE_AGENT);
      __hip_atomic_store(&s[2], g + 1, __ATOMIC_RELEASE,
                         __HIP_MEMORY_SCOPE_AGENT);
    } else {
      int it = 0;
      while (__hip_atomic_load(&s[2], __ATOMIC_ACQUIRE,
                               __HIP_MEMORY_SCOPE_AGENT) == g) {
        __builtin_amdgcn_s_sleep(2);
        if (++it > (1 << 25)) break;  // safety valve: fail, don't hang
      }
    }
    __threadfence();  // acquire: invalidate stale cached data
  }
  __syncthreads();
}

// ---- phase A bodies ------------------------------------------------------------
__device__ void conv_qdkd_body(const Args& a, int vb) {
  const int wave = threadIdx.x >> 6, lane = threadIdx.x & 63;
  const int t = vb * 4 + wave;
  const float* xp = a.x + (size_t)t * C_DIM;
  bf16* xbp = a.xb + (size_t)t * C_DIM;
  float aq[8] = {}, ak[8] = {};
#pragma unroll
  for (int i = 0; i < 16; ++i) {
    const int c = i * 64 + lane;
    float xv = xp[c];
    xbp[c] = (bf16)xv;
    float4 wq0 = *(const float4*)(a.Wdq + (size_t)c * K_LCP);
    float4 wq1 = *(const float4*)(a.Wdq + (size_t)c * K_LCP + 4);
    float4 wk0 = *(const float4*)(a.Wdk + (size_t)c * K_LCP);
    float4 wk1 = *(const float4*)(a.Wdk + (size_t)c * K_LCP + 4);
    aq[0] = fmaf(xv, wq0.x, aq[0]); aq[1] = fmaf(xv, wq0.y, aq[1]);
    aq[2] = fmaf(xv, wq0.z, aq[2]); aq[3] = fmaf(xv, wq0.w, aq[3]);
    aq[4] = fmaf(xv, wq1.x, aq[4]); aq[5] = fmaf(xv, wq1.y, aq[5]);
    aq[6] = fmaf(xv, wq1.z, aq[6]); aq[7] = fmaf(xv, wq1.w, aq[7]);
    ak[0] = fmaf(xv, wk0.x, ak[0]); ak[1] = fmaf(xv, wk0.y, ak[1]);
    ak[2] = fmaf(xv, wk0.z, ak[2]); ak[3] = fmaf(xv, wk0.w, ak[3]);
    ak[4] = fmaf(xv, wk1.x, ak[4]); ak[5] = fmaf(xv, wk1.y, ak[5]);
    ak[6] = fmaf(xv, wk1.z, ak[6]); ak[7] = fmaf(xv, wk1.w, ak[7]);
  }
#pragma unroll
  for (int j = 0; j < 8; ++j) {
#pragma unroll
    for (int off = 32; off >= 1; off >>= 1) {
      aq[j] += __shfl_xor(aq[j], off);
      ak[j] += __shfl_xor(ak[j], off);
    }
  }
  if (lane == 0) {
    *(float4*)(a.qd + (size_t)t * K_LCP) = make_float4(aq[0], aq[1], aq[2], aq[3]);
    *(float4*)(a.qd + (size_t)t * K_LCP + 4) = make_float4(aq[4], aq[5], aq[6], aq[7]);
    *(float4*)(a.kd + (size_t)t * K_LCP) = make_float4(ak[0], ak[1], ak[2], ak[3]);
    *(float4*)(a.kd + (size_t)t * K_LCP + 4) = make_float4(ak[4], ak[5], ak[6], ak[7]);
  }
}

__device__ void xpartial_body(const Args& a, int b) {
  const int t = threadIdx.x;
  f32x4 s = {0.f, 0.f, 0.f, 0.f};
  for (int r = 0; r < 64; ++r)
    s += ((const f32x4*)(a.x + (size_t)(b * 64 + r) * C_DIM))[t];
  ((f32x4*)(a.partial + (size_t)b * C_DIM))[t] = s;
}

__device__ void transpose_body(SmemU& sm, const Args& a, int idx) {
  const int z = idx >> 8;
  const float* W = (z == 0) ? a.Wq : (z == 1) ? a.Wk : (z == 2) ? a.Wv : a.Wproj;
  bf16* O = (z == 0) ? a.wqt : (z == 1) ? a.wkt : (z == 2) ? a.wvt : a.wpt;
  const int rem = idx & 255;
  const int bk = (rem >> 4) * 64;
  const int bn = (rem & 15) * 64;
  const int r = threadIdx.x >> 2;
  const int c0 = (threadIdx.x & 3) * 16;
  __syncthreads();  // protect previous virtual iteration's tile reads
  const float* src = W + (size_t)(bk + r) * C_DIM + bn + c0;
#pragma unroll
  for (int t = 0; t < 16; t += 4) {
    float4 f = *(const float4*)(src + t);
    sm.tp.tile[r][c0 + t + 0] = (bf16)f.x;
    sm.tp.tile[r][c0 + t + 1] = (bf16)f.y;
    sm.tp.tile[r][c0 + t + 2] = (bf16)f.z;
    sm.tp.tile[r][c0 + t + 3] = (bf16)f.w;
  }
  __syncthreads();
  bf16* dst = O + (size_t)(bn + r) * C_DIM + bk + c0;
#pragma unroll
  for (int t = 0; t < 16; ++t) dst[t] = sm.tp.tile[c0 + t][r];
}

// ---- phase B bodies ------------------------------------------------------------
__device__ void tilemask_body(SmemU& sm, const Args& a, int qb) {
  const int tid = threadIdx.x;
  __syncthreads();  // union reuse guard
  if (tid < 32) sm.tmask.tm[tid] = 0;
  if (tid < 16 * K_LCP)
    sm.tmask.qds[tid >> 3][tid & 7] =
        a.qd[(size_t)(qb * 16 + (tid >> 3)) * K_LCP + (tid & 7)];
  __syncthreads();
  for (int key = tid; key < T_DIM; key += 256) {
    float kv[K_LCP];
    *(float4*)&kv[0] = *(const float4*)(a.kd + (size_t)key * K_LCP);
    *(float4*)&kv[4] = *(const float4*)(a.kd + (size_t)key * K_LCP + 4);
    int any = 0;
#pragma unroll
    for (int ql = 0; ql < 16; ++ql) {
      int qg = qb * 16 + ql;
      if (key > qg) continue;
      int lcp = 0;
#pragma unroll
      for (int jj = 0; jj < K_LCP; ++jj) {
        if (sm.tmask.qds[ql][jj] == kv[jj]) lcp++;
        else break;
      }
      if (lcp >= K_LCP - 1) any = 1;
    }
    if (any) sm.tmask.tm[key >> 6] = 1;  // benign race: same value
  }
  __syncthreads();
  int anytm = 0;
#pragma unroll
  for (int i = 0; i < 32; ++i) anytm |= sm.tmask.tm[i];
  if (tid < 32) a.tilemask[qb * 32 + tid] = sm.tmask.tm[tid];
  if (tid == 0) a.allmask[qb] = !anytm;
  if (anytm) {  // flags pre-zeroed in phase A; device-scope atomics
    if (tid < 32) {
      if (sm.tmask.tm[tid]) {
        atomicOr(&a.kneed[tid >> 1], 1);
        atomicOr(&a.vneed[tid >> 1], 1);
      } else {
        atomicOr(&a.vtneed[tid], 1);
        atomicOr(&a.vneed[tid >> 1], 1);
      }
    }
    if (tid == 0) {
      atomicOr(&a.qneed[qb >> 3], 1);
      atomicOr(&a.pneed[qb >> 2], 1);
    }
  }
  __syncthreads();
}

__device__ void matvec_body(SmemU& sm, const float* vin, int npart,
                            const float* W, float* vout, float scale, int blk) {
  const int t = threadIdx.x;
  __syncthreads();  // union reuse guard
  f32x4 s = {0.f, 0.f, 0.f, 0.f};
  if (npart) {
    for (int g = 0; g < npart; ++g) s += ((const f32x4*)vin)[g * 256 + t];
  } else {
    s = ((const f32x4*)vin)[t];
  }
  s *= scale;
  *(f32x4*)&sm.mv.xm[t * 4] = s;
  __syncthreads();
  const int j = blk * 64 + (t & 63);
  const int p = t >> 6;
  float acc = 0.f;
  for (int c = p * 256; c < p * 256 + 256; ++c)
    acc = fmaf(sm.mv.xm[c], W[(size_t)c * C_DIM + j], acc);
  sm.mv.red[p][t & 63] = acc;
  __syncthreads();
  if (t < 64)
    vout[blk * 64 + t] =
        (sm.mv.red[0][t] + sm.mv.red[1][t]) + (sm.mv.red[2][t] + sm.mv.red[3][t]);
  __syncthreads();
}

// ---- MFMA GEMM body (m97 structure) w/ RoPE+RMS epilogue & fused vtsum ---------
template <int TMt, int MI, int NA>
__device__ void gemm_body(SmemU& sm, const Args& a, const bf16* A,
                          const bf16* Bt, void* Cv, int bx, int by, int z,
                          int mode) {
  bf16* As = sm.gemm.As;
  bf16* Bs = sm.gemm.Bs;
  const int tid = threadIdx.x;
  const int Kd = C_DIM, N = C_DIM;
  const int bm = by * TMt;
  const int bn = bx * 128;
  const int wave = tid >> 6, lane = tid & 63;
  const int lr = lane >> 2;
  const int lc = (lane & 3) * 8;
  bf16* gA = (bf16*)(A + (size_t)(bm + wave * 16 * NA + lr) * Kd + lc);
  bf16* gB = (bf16*)(Bt + (size_t)(bn + wave * 32 + lr) * Kd + lc);
  bf16* lA = As + wave * 512 * NA;
  bf16* lB = Bs + wave * 1024;
  const int wr = (wave >> 1) * (MI * 16);
  const int wc = (wave & 1) * 64;
  const int fm = lane & 15;
  const int fk_ = (lane >> 4) * 8;

  f32x4 acc[MI][4] = {};
  for (int k0 = 0; k0 < Kd; k0 += 32) {
    __syncthreads();
#pragma unroll
    for (int u = 0; u < NA; ++u)
      __builtin_amdgcn_global_load_lds(
          (__attribute__((address_space(1))) void*)(gA + (size_t)u * 16 * Kd + k0),
          (__attribute__((address_space(3))) void*)(lA + u * 512), 16, 0, 0);
#pragma unroll
    for (int u = 0; u < 2; ++u)
      __builtin_amdgcn_global_load_lds(
          (__attribute__((address_space(1))) void*)(gB + (size_t)u * 16 * Kd + k0),
          (__attribute__((address_space(3))) void*)(lB + u * 1024 / 2), 16, 0, 0);
    __syncthreads();
    bf16x8 af[MI], bfr[4];
#pragma unroll
    for (int i = 0; i < MI; ++i)
      af[i] = *(const bf16x8*)(As + (size_t)(wr + i * 16 + fm) * 32 + fk_);
#pragma unroll
    for (int j = 0; j < 4; ++j)
      bfr[j] = *(const bf16x8*)(Bs + (size_t)(wc + j * 16 + fm) * 32 + fk_);
#pragma unroll
    for (int i = 0; i < MI; ++i)
#pragma unroll
      for (int j = 0; j < 4; ++j)
        acc[i][j] = __builtin_amdgcn_mfma_f32_16x16x32_bf16(af[i], bfr[j],
                                                            acc[i][j], 0, 0, 0);
  }
  __syncthreads();  // protect LDS before another body reuses the union
  const int cq = (lane >> 4) * 4;
  if (mode && z < 2) {
    bf16* C = (bf16*)Cv;
#pragma unroll
    for (int i = 0; i < MI; ++i)
#pragma unroll
      for (int r = 0; r < 4; ++r) {
        const int t = bm + wr + i * 16 + cq + r;
        float c0 = a.cosT[(size_t)t * 32 + fm], s0 = a.sinT[(size_t)t * 32 + fm];
        float c1 = a.cosT[(size_t)t * 32 + 16 + fm];
        float s1 = a.sinT[(size_t)t * 32 + 16 + fm];
        float a0 = acc[i][0][r], a1 = acc[i][1][r];
        float a2 = acc[i][2][r], a3 = acc[i][3][r];
        float o0 = a0 * c0 - a2 * s0, o2 = a0 * s0 + a2 * c0;
        float o1 = a1 * c1 - a3 * s1, o3 = a1 * s1 + a3 * c1;
        float ss = o0 * o0 + o1 * o1 + o2 * o2 + o3 * o3;
        ss += __shfl_xor(ss, 1);
        ss += __shfl_xor(ss, 2);
        ss += __shfl_xor(ss, 4);
        ss += __shfl_xor(ss, 8);
        float rn = 1.0f / sqrtf(ss * (1.0f / 64.0f) + 1e-6f);
        size_t base = (size_t)t * N + bn + wc + fm;
        C[base + 0] = (bf16)(o0 * rn);
        C[base + 16] = (bf16)(o1 * rn);
        C[base + 32] = (bf16)(o2 * rn);
        C[base + 48] = (bf16)(o3 * rn);
      }
  } else if (mode) {  // V slice: bf16 store + fused vtsum
    bf16* C = (bf16*)Cv;
#pragma unroll
    for (int i = 0; i < MI; ++i)
#pragma unroll
      for (int r = 0; r < 4; ++r) {
        size_t base = (size_t)(bm + wr + i * 16 + cq + r) * N + bn + wc + fm;
#pragma unroll
        for (int j = 0; j < 4; ++j) C[base + j * 16] = (bf16)acc[i][j][r];
      }
    const int kt = (bm + wr) >> 6;  // MI==4: wave quadrant = one 64-row kt tile
#pragma unroll
    for (int j = 0; j < 4; ++j) {
      float s = 0.f;
#pragma unroll
      for (int i = 0; i < MI; ++i)
#pragma unroll
        for (int r = 0; r < 4; ++r) s += acc[i][j][r];
      s += __shfl_xor(s, 16);
      s += __shfl_xor(s, 32);
      if ((lane >> 4) == 0)
        a.vtsum[(size_t)kt * C_DIM + bn + wc + j * 16 + fm] = s;
    }
  } else {  // proj: float store
    float* C = (float*)Cv;
#pragma unroll
    for (int i = 0; i < MI; ++i)
#pragma unroll
      for (int r = 0; r < 4; ++r) {
        size_t base = (size_t)(bm + wr + i * 16 + cq + r) * N + bn + wc + fm;
#pragma unroll
        for (int j = 0; j < 4; ++j) C[base + j * 16] = acc[i][j][r];
      }
  }
}

// ---- attention body ------------------------------------------------------------
__device__ void attn_body(SmemU& sm, const Args& a, int qb, int h) {
  const int q0 = qb * 16;
  const int tid = threadIdx.x;
  const int q_l = tid >> 4;
  const int sub = tid & 15;

  if (a.allmask[qb]) {
    if (a.pneed[qb >> 2]) {
      f32x4 vm = *(const f32x4*)(a.vmean + h * HD_DIM + sub * 4);
      bf16x4 o = {(bf16)vm[0], (bf16)vm[1], (bf16)vm[2], (bf16)vm[3]};
      *(bf16x4*)(a.xb + (size_t)(q0 + q_l) * C_DIM + h * HD_DIM + sub * 4) = o;
    }
    return;
  }

  __syncthreads();  // union reuse guard
  {
    int r = tid >> 4, c4 = (tid & 15) * 4;
    bf16x4 t4 = *(const bf16x4*)(a.qB + (size_t)(q0 + r) * C_DIM + h * HD_DIM + c4);
    sm.attn.qs[r][c4 + 0] = (float)t4[0] * 0.125f;
    sm.attn.qs[r][c4 + 1] = (float)t4[1] * 0.125f;
    sm.attn.qs[r][c4 + 2] = (float)t4[2] * 0.125f;
    sm.attn.qs[r][c4 + 3] = (float)t4[3] * 0.125f;
    if (tid < 16 * K_LCP)
      sm.attn.qds[tid >> 3][tid & 7] =
          a.qd[(size_t)(q0 + (tid >> 3)) * K_LCP + (tid & 7)];
  }
  __syncthreads();

  float m = -INFINITY;
  float l = 0.f;
  float acc[4] = {0.f, 0.f, 0.f, 0.f};

  for (int kt = 0; kt < 32; ++kt) {
    if (!a.tilemask[qb * 32 + kt]) {
      if (m <= NEG_VAL) {
        m = NEG_VAL;
        l += 64.0f;
        f32x4 vt =
            *(const f32x4*)(a.vtsum + (size_t)kt * C_DIM + h * HD_DIM + sub * 4);
        acc[0] += vt[0]; acc[1] += vt[1]; acc[2] += vt[2]; acc[3] += vt[3];
      }
      continue;
    }
    const int k0 = kt * 64;
    __syncthreads();
#pragma unroll
    for (int it = 0; it < 4; ++it) {
      int i = tid + it * 256;
      int row = i >> 4, c4 = (i & 15) * 4;
      bf16x4 kv =
          *(const bf16x4*)(a.kB + (size_t)(k0 + row) * C_DIM + h * HD_DIM + c4);
      bf16x4 vv =
          *(const bf16x4*)(a.vB + (size_t)(k0 + row) * C_DIM + h * HD_DIM + c4);
      sm.attn.ks[row][c4 + 0] = (float)kv[0];
      sm.attn.ks[row][c4 + 1] = (float)kv[1];
      sm.attn.ks[row][c4 + 2] = (float)kv[2];
      sm.attn.ks[row][c4 + 3] = (float)kv[3];
      sm.attn.vs[row][c4 + 0] = (float)vv[0];
      sm.attn.vs[row][c4 + 1] = (float)vv[1];
      sm.attn.vs[row][c4 + 2] = (float)vv[2];
      sm.attn.vs[row][c4 + 3] = (float)vv[3];
    }
#pragma unroll
    for (int it = 0; it < 2; ++it) {
      int i = tid + it * 256;
      sm.attn.kds[i >> 3][i & 7] = a.kd[(size_t)(k0 + (i >> 3)) * K_LCP + (i & 7)];
    }
    __syncthreads();

    const int kb = sub * 4;
    bool msk[4];
#pragma unroll
    for (int j = 0; j < 4; ++j) {
      int kg = k0 + kb + j;
      int lcp = 0;
#pragma unroll
      for (int jj = 0; jj < K_LCP; ++jj) {
        if (sm.attn.qds[q_l][jj] == sm.attn.kds[kb + j][jj]) lcp++;
        else break;
      }
      msk[j] = (lcp >= K_LCP - 1) && (kg <= q0 + q_l);
    }
    float s[4] = {0.f, 0.f, 0.f, 0.f};
#pragma unroll
    for (int d4 = 0; d4 < 16; ++d4) {
      float4 q4 = *(const float4*)&sm.attn.qs[q_l][d4 * 4];
#pragma unroll
      for (int j = 0; j < 4; ++j) {
        float4 k4 = *(const float4*)&sm.attn.ks[kb + j][d4 * 4];
        s[j] = fmaf(q4.x, k4.x, s[j]);
        s[j] = fmaf(q4.y, k4.y, s[j]);
        s[j] = fmaf(q4.z, k4.z, s[j]);
        s[j] = fmaf(q4.w, k4.w, s[j]);
      }
    }
    float tmax = NEG_VAL;
#pragma unroll
    for (int j = 0; j < 4; ++j) {
      s[j] = msk[j] ? s[j] : NEG_VAL;
      tmax = fmaxf(tmax, s[j]);
    }
#pragma unroll
    for (int off = 1; off < 16; off <<= 1) tmax = fmaxf(tmax, __shfl_xor(tmax, off));
    float m_new = fmaxf(m, tmax);
    float alpha = expf(m - m_new);
    float lsum = 0.f;
#pragma unroll
    for (int j = 0; j < 4; ++j) {
      float p = expf(s[j] - m_new);
      sm.attn.sc[q_l][kb + j] = p;
      lsum += p;
    }
#pragma unroll
    for (int off = 1; off < 16; off <<= 1) lsum += __shfl_xor(lsum, off);
    l = l * alpha + lsum;
    m = m_new;
    acc[0] *= alpha; acc[1] *= alpha; acc[2] *= alpha; acc[3] *= alpha;
    __syncthreads();
#pragma unroll 8
    for (int kk = 0; kk < 64; ++kk) {
      float w = sm.attn.sc[q_l][kk];
      const float4 v4 = *(const float4*)&sm.attn.vs[kk][sub * 4];
      acc[0] = fmaf(w, v4.x, acc[0]);
      acc[1] = fmaf(w, v4.y, acc[1]);
      acc[2] = fmaf(w, v4.z, acc[2]);
      acc[3] = fmaf(w, v4.w, acc[3]);
    }
  }

  const float inv_l = 1.0f / l;
  bf16x4 o = {(bf16)(acc[0] * inv_l), (bf16)(acc[1] * inv_l),
              (bf16)(acc[2] * inv_l), (bf16)(acc[3] * inv_l)};
  *(bf16x4*)(a.xb + (size_t)(q0 + q_l) * C_DIM + h * HD_DIM + sub * 4) = o;
  __syncthreads();
}

__device__ void bcast_body(const Args& a, int b) {
  f32x4 v = ((const f32x4*)a.rowout)[threadIdx.x];
#pragma unroll
  for (int r = 0; r < 8; ++r) {
    const int row = b * 8 + r;
    if (a.pneed[row >> 6]) continue;
    ((f32x4*)(a.out + (size_t)row * C_DIM))[threadIdx.x] = v;
  }
}

// ---- the single persistent kernel (ordinary launch, software grid barrier) ----
__global__ __launch_bounds__(256, 1) void mega(Args a) {
  const int nb = gridDim.x;
  __shared__ SmemU sm;

  // init handshake: ws is poisoned 0xAA each launch; block 0 resets barrier state
  if (blockIdx.x == 0 && threadIdx.x == 0) {
    __hip_atomic_store(&a.sync[1], 0, __ATOMIC_RELAXED, __HIP_MEMORY_SCOPE_AGENT);
    __hip_atomic_store(&a.sync[2], 0, __ATOMIC_RELAXED, __HIP_MEMORY_SCOPE_AGENT);
    __hip_atomic_store(&a.sync[0], SYNC_MAGIC, __ATOMIC_RELEASE,
                       __HIP_MEMORY_SCOPE_AGENT);
  }
  if (threadIdx.x == 0) {
    int it = 0;
    while (__hip_atomic_load(&a.sync[0], __ATOMIC_ACQUIRE,
                             __HIP_MEMORY_SCOPE_AGENT) != SYNC_MAGIC) {
      __builtin_amdgcn_s_sleep(2);
      if (++it > (1 << 25)) break;
    }
  }
  __syncthreads();

  // Phase A: convert+qdkd (0..511), xpartial+flagzero (512..543), transposes (544..1567)
  for (int vb = blockIdx.x; vb < 1568; vb += nb) {
    if (vb < 512) {
      conv_qdkd_body(a, vb);
    } else if (vb < 544) {
      if (vb == 512 && threadIdx.x < 116) a.qneed[threadIdx.x] = 0;
      xpartial_body(a, vb - 512);
    } else {
      transpose_body(sm, a, vb - 544);
    }
  }
  gsync(a.sync, nb);

  // Phase B: tilemask+flags (0..127), vmean matvec (128..143)
  for (int vb = blockIdx.x; vb < 144; vb += nb) {
    if (vb < 128)
      tilemask_body(sm, a, vb);
    else
      matvec_body(sm, a.partial, 32, a.Wv, a.vmean, 1.0f / 2048.0f, vb - 128);
  }
  gsync(a.sync, nb);

  // Phase C: flagged QKV GEMM (0..383) + rowout matvec (384..399)
  for (int vb = blockIdx.x; vb < 400; vb += nb) {
    if (vb < 384) {
      int z = vb >> 7, r = vb & 127, by = r >> 3, bx = r & 7;
      const int* f = (z == 0) ? a.qneed : (z == 1) ? a.kneed : a.vneed;
      if (f[by]) {
        const bf16* Bt = (z == 0) ? a.wqt : (z == 1) ? a.wkt : a.wvt;
        void* C = (z == 0) ? (void*)a.qB : (z == 1) ? (void*)a.kB : (void*)a.vB;
        gemm_body<128, 4, 2>(sm, a, a.xb, Bt, C, bx, by, z, 1);
      }
    } else {
      matvec_body(sm, a.vmean, 0, a.Wproj, a.rowout, 1.0f, vb - 384);
    }
  }
  gsync(a.sync, nb);

  // Phase D: attention (y written into a.xb; x(bf16) is dead)
  for (int vb = blockIdx.x; vb < 2048; vb += nb)
    attn_body(sm, a, vb >> 4, vb & 15);
  gsync(a.sync, nb);

  // Phase E: flagged proj GEMM (0..255) + bcast (256..511)
  for (int vb = blockIdx.x; vb < 512; vb += nb) {
    if (vb < 256) {
      int by = vb >> 3, bx = vb & 7;
      if (a.pneed[by])
        gemm_body<64, 2, 1>(sm, a, a.xb, a.wpt, (void*)a.out, bx, by, 0, 0);
    } else {
      bcast_body(a, vb - 256);
    }
  }
}

extern "C" void kernel_launch(void* const* d_in, const int* in_sizes, int n_in,
                              void* d_out, int out_size, void* d_ws, size_t ws_size,
                              hipStream_t stream) {
  char* ws = (char*)d_ws;
  const size_t TC2 = (size_t)T_DIM * C_DIM * 2;
  const size_t CC2 = (size_t)C_DIM * C_DIM * 2;

  Args a;
  a.x = (const float*)d_in[0];
  a.cosT = (const float*)d_in[1];
  a.sinT = (const float*)d_in[2];
  a.Wq = (const float*)d_in[3];
  a.Wk = (const float*)d_in[4];
  a.Wv = (const float*)d_in[5];
  a.Wproj = (const float*)d_in[6];
  a.Wdq = (const float*)d_in[7];
  a.Wdk = (const float*)d_in[8];
  a.out = (float*)d_out;
  a.xb = (bf16*)(ws + 0);
  a.wqt = (bf16*)(ws + TC2);
  a.wkt = (bf16*)(ws + TC2 + CC2);
  a.wvt = (bf16*)(ws + TC2 + 2 * CC2);
  a.wpt = (bf16*)(ws + TC2 + 3 * CC2);
  a.qB = (bf16*)(ws + TC2 + 4 * CC2);
  a.kB = (bf16*)(ws + 2 * TC2 + 4 * CC2);
  a.vB = (bf16*)(ws + 3 * TC2 + 4 * CC2);
  char* p2 = ws + 4 * TC2 + 4 * CC2;
  a.qd = (float*)p2;        p2 += (size_t)T_DIM * K_LCP * 4;
  a.kd = (float*)p2;        p2 += (size_t)T_DIM * K_LCP * 4;
  a.vtsum = (float*)p2;     p2 += 32 * C_DIM * 4;
  a.vmean = (float*)p2;     p2 += C_DIM * 4;
  a.partial = (float*)p2;   p2 += 32 * C_DIM * 4;
  a.rowout = (float*)p2;    p2 += C_DIM * 4;
  a.tilemask = (int*)p2;    p2 += (T_DIM / 16) * 32 * 4;
  a.allmask = (int*)p2;     p2 += (T_DIM / 16) * 4;
  // contiguous flag block (116 ints), zeroed in phase A
  a.qneed = (int*)p2;       p2 += 16 * 4;
  a.kneed = (int*)p2;       p2 += 16 * 4;
  a.vneed = (int*)p2;       p2 += 16 * 4;
  a.vtneed = (int*)p2;      p2 += 32 * 4;
  a.pneed = (int*)p2;       p2 += 32 * 4;
  a.sync = (int*)p2;        p2 += 4 * 4;

  mega<<<dim3(256), dim3(256), 0, stream>>>(a);
}

// Round 10
// 121.362 us; speedup vs baseline: 2.3453x; 2.3453x over previous
//
#include <hip/hip_runtime.h>
#include <math.h>

#define T_DIM 2048
#define C_DIM 1024
#define H_NUM 16
#define HD_DIM 64
#define K_LCP 8
#define NEG_VAL -1.0e9f

typedef __bf16 bf16;
typedef __bf16 bf16x4 __attribute__((ext_vector_type(4)));
typedef __bf16 bf16x8 __attribute__((ext_vector_type(8)));
typedef float f32x4 __attribute__((ext_vector_type(4)));

// ---- A: conv+qdkd (0..511), xpartial+flagzero (512..543), transposes (544..1567)
__global__ __launch_bounds__(256) void fused_a(
    const float* __restrict__ x, const float* __restrict__ Wdq,
    const float* __restrict__ Wdk, const float* __restrict__ Wq,
    const float* __restrict__ Wk, const float* __restrict__ Wv,
    const float* __restrict__ Wproj, bf16* __restrict__ xb,
    float* __restrict__ qd, float* __restrict__ kd, float* __restrict__ partial,
    int* __restrict__ flags, bf16* __restrict__ wqt, bf16* __restrict__ wkt,
    bf16* __restrict__ wvt, bf16* __restrict__ wpt) {
  __shared__ bf16 tile[64][65];
  const int vb = blockIdx.x;
  const int tid = threadIdx.x;
  if (vb < 512) {  // convert + qd/kd, one wave per row
    const int wave = tid >> 6, lane = tid & 63;
    const int t = vb * 4 + wave;
    const float* xp = x + (size_t)t * C_DIM;
    bf16* xbp = xb + (size_t)t * C_DIM;
    float aq[8] = {}, ak[8] = {};
#pragma unroll
    for (int i = 0; i < 16; ++i) {
      const int c = i * 64 + lane;
      float xv = xp[c];
      xbp[c] = (bf16)xv;
      float4 wq0 = *(const float4*)(Wdq + (size_t)c * K_LCP);
      float4 wq1 = *(const float4*)(Wdq + (size_t)c * K_LCP + 4);
      float4 wk0 = *(const float4*)(Wdk + (size_t)c * K_LCP);
      float4 wk1 = *(const float4*)(Wdk + (size_t)c * K_LCP + 4);
      aq[0] = fmaf(xv, wq0.x, aq[0]); aq[1] = fmaf(xv, wq0.y, aq[1]);
      aq[2] = fmaf(xv, wq0.z, aq[2]); aq[3] = fmaf(xv, wq0.w, aq[3]);
      aq[4] = fmaf(xv, wq1.x, aq[4]); aq[5] = fmaf(xv, wq1.y, aq[5]);
      aq[6] = fmaf(xv, wq1.z, aq[6]); aq[7] = fmaf(xv, wq1.w, aq[7]);
      ak[0] = fmaf(xv, wk0.x, ak[0]); ak[1] = fmaf(xv, wk0.y, ak[1]);
      ak[2] = fmaf(xv, wk0.z, ak[2]); ak[3] = fmaf(xv, wk0.w, ak[3]);
      ak[4] = fmaf(xv, wk1.x, ak[4]); ak[5] = fmaf(xv, wk1.y, ak[5]);
      ak[6] = fmaf(xv, wk1.z, ak[6]); ak[7] = fmaf(xv, wk1.w, ak[7]);
    }
#pragma unroll
    for (int j = 0; j < 8; ++j) {
#pragma unroll
      for (int off = 32; off >= 1; off >>= 1) {
        aq[j] += __shfl_xor(aq[j], off);
        ak[j] += __shfl_xor(ak[j], off);
      }
    }
    if (lane == 0) {
      *(float4*)(qd + (size_t)t * K_LCP) = make_float4(aq[0], aq[1], aq[2], aq[3]);
      *(float4*)(qd + (size_t)t * K_LCP + 4) = make_float4(aq[4], aq[5], aq[6], aq[7]);
      *(float4*)(kd + (size_t)t * K_LCP) = make_float4(ak[0], ak[1], ak[2], ak[3]);
      *(float4*)(kd + (size_t)t * K_LCP + 4) = make_float4(ak[4], ak[5], ak[6], ak[7]);
    }
  } else if (vb < 544) {  // xpartial arm (+ flag zeroing in first block)
    const int b = vb - 512;
    if (b == 0 && tid < 112) flags[tid] = 0;
    f32x4 s = {0.f, 0.f, 0.f, 0.f};
    for (int r = 0; r < 64; ++r)
      s += ((const f32x4*)(x + (size_t)(b * 64 + r) * C_DIM))[tid];
    ((f32x4*)(partial + (size_t)b * C_DIM))[tid] = s;
  } else {  // transpose+convert weights (unconditional)
    const int idx = vb - 544;
    const int z = idx >> 8;
    const float* W = (z == 0) ? Wq : (z == 1) ? Wk : (z == 2) ? Wv : Wproj;
    bf16* O = (z == 0) ? wqt : (z == 1) ? wkt : (z == 2) ? wvt : wpt;
    const int rem = idx & 255;
    const int bk = (rem >> 4) * 64;
    const int bn = (rem & 15) * 64;
    const int r = tid >> 2;
    const int c0 = (tid & 3) * 16;
    const float* src = W + (size_t)(bk + r) * C_DIM + bn + c0;
#pragma unroll
    for (int t = 0; t < 16; t += 4) {
      float4 f = *(const float4*)(src + t);
      tile[r][c0 + t + 0] = (bf16)f.x;
      tile[r][c0 + t + 1] = (bf16)f.y;
      tile[r][c0 + t + 2] = (bf16)f.z;
      tile[r][c0 + t + 3] = (bf16)f.w;
    }
    __syncthreads();
    bf16* dst = O + (size_t)(bn + r) * C_DIM + bk + c0;
#pragma unroll
    for (int t = 0; t < 16; ++t) dst[t] = tile[c0 + t][r];
  }
}

// ---- B: tilemask + atomic need flags (0..127), vmean matvec (128..143) ---------
__global__ __launch_bounds__(256) void fused_b(
    const float* __restrict__ qd, const float* __restrict__ kd,
    const float* __restrict__ partial, const float* __restrict__ Wv,
    int* __restrict__ tilemask, int* __restrict__ allmask,
    float* __restrict__ vmean, int* __restrict__ qneed, int* __restrict__ kneed,
    int* __restrict__ vneed, int* __restrict__ pneed) {
  const int tid = threadIdx.x;
  if (blockIdx.x >= 128) {  // vmean = (colmean x) @ Wv
    __shared__ float xm[C_DIM];
    __shared__ float red[4][64];
    const int blk = blockIdx.x - 128;
    f32x4 s = {0.f, 0.f, 0.f, 0.f};
    for (int g = 0; g < 32; ++g) s += ((const f32x4*)partial)[g * 256 + tid];
    s *= (1.0f / 2048.0f);
    *(f32x4*)&xm[tid * 4] = s;
    __syncthreads();
    const int j = blk * 64 + (tid & 63);
    const int p = tid >> 6;
    float acc = 0.f;
    for (int c = p * 256; c < p * 256 + 256; ++c)
      acc = fmaf(xm[c], Wv[(size_t)c * C_DIM + j], acc);
    red[p][tid & 63] = acc;
    __syncthreads();
    if (tid < 64)
      vmean[blk * 64 + tid] =
          (red[0][tid] + red[1][tid]) + (red[2][tid] + red[3][tid]);
    return;
  }
  const int qb = blockIdx.x;
  __shared__ float qds[16][K_LCP];
  __shared__ int tm[32];
  if (tid < 32) tm[tid] = 0;
  if (tid < 16 * K_LCP)
    qds[tid >> 3][tid & 7] = qd[(size_t)(qb * 16 + (tid >> 3)) * K_LCP + (tid & 7)];
  __syncthreads();
  for (int key = tid; key < T_DIM; key += 256) {
    float kv[K_LCP];
    *(float4*)&kv[0] = *(const float4*)(kd + (size_t)key * K_LCP);
    *(float4*)&kv[4] = *(const float4*)(kd + (size_t)key * K_LCP + 4);
    int any = 0;
#pragma unroll
    for (int ql = 0; ql < 16; ++ql) {
      int qg = qb * 16 + ql;
      if (key > qg) continue;
      int lcp = 0;
#pragma unroll
      for (int jj = 0; jj < K_LCP; ++jj) {
        if (qds[ql][jj] == kv[jj]) lcp++;
        else break;
      }
      if (lcp >= K_LCP - 1) any = 1;
    }
    if (any) tm[key >> 6] = 1;  // benign race: same value
  }
  __syncthreads();
  int anytm = 0;
#pragma unroll
  for (int i = 0; i < 32; ++i) anytm |= tm[i];
  if (tid < 32) tilemask[qb * 32 + tid] = tm[tid];
  if (tid == 0) allmask[qb] = !anytm;
  if (anytm) {  // flags pre-zeroed in launch A; device-scope atomics
    if (tid < 32) {
      if (tm[tid]) atomicOr(&kneed[tid >> 1], 1);
      atomicOr(&vneed[tid >> 1], 1);
    }
    if (tid == 0) {
      atomicOr(&qneed[qb >> 3], 1);
      atomicOr(&pneed[qb >> 2], 1);
    }
  }
}

// ---- MFMA GEMM body (m97 structure) --------------------------------------------
template <int TMt, int MI, int NA>
__device__ void gemm_body(bf16* As, bf16* Bs, const bf16* A, const bf16* Bt,
                          void* Cv, int bx, int by, int z, int mode,
                          const float* cosT, const float* sinT, float* vtsum) {
  const int tid = threadIdx.x;
  const int Kd = C_DIM, N = C_DIM;
  const int bm = by * TMt;
  const int bn = bx * 128;
  const int wave = tid >> 6, lane = tid & 63;
  const int lr = lane >> 2;
  const int lc = (lane & 3) * 8;
  bf16* gA = (bf16*)(A + (size_t)(bm + wave * 16 * NA + lr) * Kd + lc);
  bf16* gB = (bf16*)(Bt + (size_t)(bn + wave * 32 + lr) * Kd + lc);
  bf16* lA = As + wave * 512 * NA;
  bf16* lB = Bs + wave * 1024;
  const int wr = (wave >> 1) * (MI * 16);
  const int wc = (wave & 1) * 64;
  const int fm = lane & 15;
  const int fk_ = (lane >> 4) * 8;

  f32x4 acc[MI][4] = {};
  for (int k0 = 0; k0 < Kd; k0 += 32) {
    __syncthreads();
#pragma unroll
    for (int u = 0; u < NA; ++u)
      __builtin_amdgcn_global_load_lds(
          (__attribute__((address_space(1))) void*)(gA + (size_t)u * 16 * Kd + k0),
          (__attribute__((address_space(3))) void*)(lA + u * 512), 16, 0, 0);
#pragma unroll
    for (int u = 0; u < 2; ++u)
      __builtin_amdgcn_global_load_lds(
          (__attribute__((address_space(1))) void*)(gB + (size_t)u * 16 * Kd + k0),
          (__attribute__((address_space(3))) void*)(lB + u * 512), 16, 0, 0);
    __syncthreads();
    bf16x8 af[MI], bfr[4];
#pragma unroll
    for (int i = 0; i < MI; ++i)
      af[i] = *(const bf16x8*)(As + (size_t)(wr + i * 16 + fm) * 32 + fk_);
#pragma unroll
    for (int j = 0; j < 4; ++j)
      bfr[j] = *(const bf16x8*)(Bs + (size_t)(wc + j * 16 + fm) * 32 + fk_);
#pragma unroll
    for (int i = 0; i < MI; ++i)
#pragma unroll
      for (int j = 0; j < 4; ++j)
        acc[i][j] = __builtin_amdgcn_mfma_f32_16x16x32_bf16(af[i], bfr[j],
                                                            acc[i][j], 0, 0, 0);
  }
  const int cq = (lane >> 4) * 4;
  if (mode && z < 2) {  // q/k: fused RoPE + RMS epilogue, bf16 out
    bf16* C = (bf16*)Cv;
#pragma unroll
    for (int i = 0; i < MI; ++i)
#pragma unroll
      for (int r = 0; r < 4; ++r) {
        const int t = bm + wr + i * 16 + cq + r;
        float c0 = cosT[(size_t)t * 32 + fm], s0 = sinT[(size_t)t * 32 + fm];
        float c1 = cosT[(size_t)t * 32 + 16 + fm];
        float s1 = sinT[(size_t)t * 32 + 16 + fm];
        float a0 = acc[i][0][r], a1 = acc[i][1][r];
        float a2 = acc[i][2][r], a3 = acc[i][3][r];
        float o0 = a0 * c0 - a2 * s0, o2 = a0 * s0 + a2 * c0;
        float o1 = a1 * c1 - a3 * s1, o3 = a1 * s1 + a3 * c1;
        float ss = o0 * o0 + o1 * o1 + o2 * o2 + o3 * o3;
        ss += __shfl_xor(ss, 1);
        ss += __shfl_xor(ss, 2);
        ss += __shfl_xor(ss, 4);
        ss += __shfl_xor(ss, 8);
        float rn = 1.0f / sqrtf(ss * (1.0f / 64.0f) + 1e-6f);
        size_t base = (size_t)t * N + bn + wc + fm;
        C[base + 0] = (bf16)(o0 * rn);
        C[base + 16] = (bf16)(o1 * rn);
        C[base + 32] = (bf16)(o2 * rn);
        C[base + 48] = (bf16)(o3 * rn);
      }
  } else if (mode) {  // V: bf16 out + fused vtsum (fp32 accs)
    bf16* C = (bf16*)Cv;
#pragma unroll
    for (int i = 0; i < MI; ++i)
#pragma unroll
      for (int r = 0; r < 4; ++r) {
        size_t base = (size_t)(bm + wr + i * 16 + cq + r) * N + bn + wc + fm;
#pragma unroll
        for (int j = 0; j < 4; ++j) C[base + j * 16] = (bf16)acc[i][j][r];
      }
    const int kt = (bm + wr) >> 6;  // MI==4: wave quadrant = one 64-row kt tile
#pragma unroll
    for (int j = 0; j < 4; ++j) {
      float s = 0.f;
#pragma unroll
      for (int i = 0; i < MI; ++i)
#pragma unroll
        for (int r = 0; r < 4; ++r) s += acc[i][j][r];
      s += __shfl_xor(s, 16);
      s += __shfl_xor(s, 32);
      if ((lane >> 4) == 0)
        vtsum[(size_t)kt * C_DIM + bn + wc + j * 16 + fm] = s;
    }
  } else {  // proj: float out
    float* C = (float*)Cv;
#pragma unroll
    for (int i = 0; i < MI; ++i)
#pragma unroll
      for (int r = 0; r < 4; ++r) {
        size_t base = (size_t)(bm + wr + i * 16 + cq + r) * N + bn + wc + fm;
#pragma unroll
        for (int j = 0; j < 4; ++j) C[base + j * 16] = acc[i][j][r];
      }
  }
}

// ---- C: flagged QKV GEMM (0..383) + rowout matvec (384..399) -------------------
__global__ __launch_bounds__(256) void phase_c(
    const bf16* __restrict__ xb, const bf16* __restrict__ wqt,
    const bf16* __restrict__ wkt, const bf16* __restrict__ wvt,
    bf16* __restrict__ qB, bf16* __restrict__ kB, bf16* __restrict__ vB,
    float* __restrict__ vtsum, const float* __restrict__ cosT,
    const float* __restrict__ sinT, const int* __restrict__ qneed,
    const int* __restrict__ kneed, const int* __restrict__ vneed,
    const float* __restrict__ vmean, const float* __restrict__ Wproj,
    float* __restrict__ rowout) {
  __shared__ __align__(16) bf16 As[128 * 32];
  __shared__ __align__(16) bf16 Bs[128 * 32];
  const int vb = blockIdx.x;
  const int tid = threadIdx.x;
  if (vb < 384) {
    const int z = vb >> 7, r = vb & 127, by = r >> 3, bx = r & 7;
    const int* f = (z == 0) ? qneed : (z == 1) ? kneed : vneed;
    if (!f[by]) return;
    const bf16* Bt = (z == 0) ? wqt : (z == 1) ? wkt : wvt;
    void* C = (z == 0) ? (void*)qB : (z == 1) ? (void*)kB : (void*)vB;
    gemm_body<128, 4, 2>(As, Bs, xb, Bt, C, bx, by, z, 1, cosT, sinT, vtsum);
  } else {  // rowout = vmean @ Wproj
    __shared__ float xm[C_DIM];
    __shared__ float red[4][64];
    const int blk = vb - 384;
    f32x4 s = ((const f32x4*)vmean)[tid];
    *(f32x4*)&xm[tid * 4] = s;
    __syncthreads();
    const int j = blk * 64 + (tid & 63);
    const int p = tid >> 6;
    float acc = 0.f;
    for (int c = p * 256; c < p * 256 + 256; ++c)
      acc = fmaf(xm[c], Wproj[(size_t)c * C_DIM + j], acc);
    red[p][tid & 63] = acc;
    __syncthreads();
    if (tid < 64)
      rowout[blk * 64 + tid] =
          (red[0][tid] + red[1][tid]) + (red[2][tid] + red[3][tid]);
  }
}

// ---- flash attention w/ tile mask, V sums, all-masked exit ---------------------
#define QT 16
#define KT 64

__global__ __launch_bounds__(256) void attn2(
    const bf16* __restrict__ q, const bf16* __restrict__ k,
    const bf16* __restrict__ v, const float* __restrict__ qd,
    const float* __restrict__ kd, const float* __restrict__ vtsum,
    const float* __restrict__ vmean, const int* __restrict__ tilemask,
    const int* __restrict__ allmask, const int* __restrict__ pneed,
    bf16* __restrict__ y) {
  const int h = blockIdx.y;
  const int qb = blockIdx.x;
  const int q0 = qb * QT;
  const int tid = threadIdx.x;
  const int q_l = tid >> 4;
  const int sub = tid & 15;

  if (allmask[qb]) {
    if (pneed[qb >> 2]) {  // y only read by proj blocks that actually run
      f32x4 vm = *(const f32x4*)(vmean + h * HD_DIM + sub * 4);
      bf16x4 o = {(bf16)vm[0], (bf16)vm[1], (bf16)vm[2], (bf16)vm[3]};
      *(bf16x4*)(y + (size_t)(q0 + q_l) * C_DIM + h * HD_DIM + sub * 4) = o;
    }
    return;
  }

  __shared__ float qs[QT][HD_DIM];
  __shared__ float qds[QT][K_LCP];
  __shared__ float ks[KT][HD_DIM];
  __shared__ float vs[KT][HD_DIM];
  __shared__ float kds[KT][K_LCP];
  __shared__ float sc[QT][KT + 4];

  {
    int r = tid >> 4, c4 = (tid & 15) * 4;
    bf16x4 t4 = *(const bf16x4*)(q + (size_t)(q0 + r) * C_DIM + h * HD_DIM + c4);
    qs[r][c4 + 0] = (float)t4[0] * 0.125f;
    qs[r][c4 + 1] = (float)t4[1] * 0.125f;
    qs[r][c4 + 2] = (float)t4[2] * 0.125f;
    qs[r][c4 + 3] = (float)t4[3] * 0.125f;
    if (tid < QT * K_LCP)
      qds[tid >> 3][tid & 7] = qd[(size_t)(q0 + (tid >> 3)) * K_LCP + (tid & 7)];
  }
  __syncthreads();

  float m = -INFINITY;
  float l = 0.f;
  float acc[4] = {0.f, 0.f, 0.f, 0.f};

  for (int kt = 0; kt < T_DIM / KT; ++kt) {
    if (!tilemask[qb * 32 + kt]) {
      if (m <= NEG_VAL) {
        m = NEG_VAL;
        l += (float)KT;
        f32x4 vt = *(const f32x4*)(vtsum + (size_t)kt * C_DIM + h * HD_DIM + sub * 4);
        acc[0] += vt[0]; acc[1] += vt[1]; acc[2] += vt[2]; acc[3] += vt[3];
      }
      continue;
    }
    const int k0 = kt * KT;
    __syncthreads();
#pragma unroll
    for (int it = 0; it < 4; ++it) {
      int i = tid + it * 256;
      int row = i >> 4, c4 = (i & 15) * 4;
      bf16x4 kv = *(const bf16x4*)(k + (size_t)(k0 + row) * C_DIM + h * HD_DIM + c4);
      bf16x4 vv = *(const bf16x4*)(v + (size_t)(k0 + row) * C_DIM + h * HD_DIM + c4);
      ks[row][c4 + 0] = (float)kv[0];
      ks[row][c4 + 1] = (float)kv[1];
      ks[row][c4 + 2] = (float)kv[2];
      ks[row][c4 + 3] = (float)kv[3];
      vs[row][c4 + 0] = (float)vv[0];
      vs[row][c4 + 1] = (float)vv[1];
      vs[row][c4 + 2] = (float)vv[2];
      vs[row][c4 + 3] = (float)vv[3];
    }
#pragma unroll
    for (int it = 0; it < 2; ++it) {
      int i = tid + it * 256;
      kds[i >> 3][i & 7] = kd[(size_t)(k0 + (i >> 3)) * K_LCP + (i & 7)];
    }
    __syncthreads();

    const int kb = sub * 4;
    bool msk[4];
#pragma unroll
    for (int j = 0; j < 4; ++j) {
      int kg = k0 + kb + j;
      int lcp = 0;
#pragma unroll
      for (int jj = 0; jj < K_LCP; ++jj) {
        if (qds[q_l][jj] == kds[kb + j][jj]) lcp++;
        else break;
      }
      msk[j] = (lcp >= K_LCP - 1) && (kg <= q0 + q_l);
    }
    float s[4] = {0.f, 0.f, 0.f, 0.f};
#pragma unroll
    for (int d4 = 0; d4 < 16; ++d4) {
      float4 q4 = *(const float4*)&qs[q_l][d4 * 4];
#pragma unroll
      for (int j = 0; j < 4; ++j) {
        float4 k4 = *(const float4*)&ks[kb + j][d4 * 4];
        s[j] = fmaf(q4.x, k4.x, s[j]);
        s[j] = fmaf(q4.y, k4.y, s[j]);
        s[j] = fmaf(q4.z, k4.z, s[j]);
        s[j] = fmaf(q4.w, k4.w, s[j]);
      }
    }
    float tmax = NEG_VAL;
#pragma unroll
    for (int j = 0; j < 4; ++j) {
      s[j] = msk[j] ? s[j] : NEG_VAL;
      tmax = fmaxf(tmax, s[j]);
    }
#pragma unroll
    for (int off = 1; off < 16; off <<= 1) tmax = fmaxf(tmax, __shfl_xor(tmax, off));
    float m_new = fmaxf(m, tmax);
    float alpha = expf(m - m_new);
    float lsum = 0.f;
#pragma unroll
    for (int j = 0; j < 4; ++j) {
      float p = expf(s[j] - m_new);
      sc[q_l][kb + j] = p;
      lsum += p;
    }
#pragma unroll
    for (int off = 1; off < 16; off <<= 1) lsum += __shfl_xor(lsum, off);
    l = l * alpha + lsum;
    m = m_new;
    acc[0] *= alpha; acc[1] *= alpha; acc[2] *= alpha; acc[3] *= alpha;
    __syncthreads();
#pragma unroll 8
    for (int kk = 0; kk < KT; ++kk) {
      float w = sc[q_l][kk];
      const float4 v4 = *(const float4*)&vs[kk][sub * 4];
      acc[0] = fmaf(w, v4.x, acc[0]);
      acc[1] = fmaf(w, v4.y, acc[1]);
      acc[2] = fmaf(w, v4.z, acc[2]);
      acc[3] = fmaf(w, v4.w, acc[3]);
    }
  }

  const float inv_l = 1.0f / l;
  bf16x4 o = {(bf16)(acc[0] * inv_l), (bf16)(acc[1] * inv_l),
              (bf16)(acc[2] * inv_l), (bf16)(acc[3] * inv_l)};
  *(bf16x4*)(y + (size_t)(q0 + q_l) * C_DIM + h * HD_DIM + sub * 4) = o;
}

// ---- E: flagged proj GEMM (0..255) + bcast (256..511) --------------------------
__global__ __launch_bounds__(256) void phase_e(
    const bf16* __restrict__ yb, const bf16* __restrict__ wpt,
    float* __restrict__ out, const int* __restrict__ pneed,
    const float* __restrict__ rowout, const float* __restrict__ cosT,
    const float* __restrict__ sinT) {
  __shared__ __align__(16) bf16 As[64 * 32];
  __shared__ __align__(16) bf16 Bs[128 * 32];
  const int vb = blockIdx.x;
  if (vb < 256) {
    const int by = vb >> 3, bx = vb & 7;
    if (!pneed[by]) return;
    gemm_body<64, 2, 1>(As, Bs, yb, wpt, (void*)out, bx, by, 2, 0, cosT, sinT,
                        nullptr);
  } else {  // broadcast rowout into fully-all-masked 64-row out blocks
    const int b = vb - 256;
    f32x4 v = ((const f32x4*)rowout)[threadIdx.x];
#pragma unroll
    for (int r = 0; r < 8; ++r) {
      const int row = b * 8 + r;
      if (pneed[row >> 6]) continue;
      ((f32x4*)(out + (size_t)row * C_DIM))[threadIdx.x] = v;
    }
  }
}

extern "C" void kernel_launch(void* const* d_in, const int* in_sizes, int n_in,
                              void* d_out, int out_size, void* d_ws, size_t ws_size,
                              hipStream_t stream) {
  const float* x = (const float*)d_in[0];
  const float* cosT = (const float*)d_in[1];
  const float* sinT = (const float*)d_in[2];
  const float* Wq = (const float*)d_in[3];
  const float* Wk = (const float*)d_in[4];
  const float* Wv = (const float*)d_in[5];
  const float* Wproj = (const float*)d_in[6];
  const float* Wdq = (const float*)d_in[7];
  const float* Wdk = (const float*)d_in[8];
  float* out = (float*)d_out;

  char* ws = (char*)d_ws;
  const size_t TC2 = (size_t)T_DIM * C_DIM * 2;
  const size_t CC2 = (size_t)C_DIM * C_DIM * 2;
  bf16* xb = (bf16*)(ws + 0);
  bf16* wqt = (bf16*)(ws + TC2);
  bf16* wkt = (bf16*)(ws + TC2 + CC2);
  bf16* wvt = (bf16*)(ws + TC2 + 2 * CC2);
  bf16* wpt = (bf16*)(ws + TC2 + 3 * CC2);
  bf16* qB = (bf16*)(ws + TC2 + 4 * CC2);
  bf16* kB = (bf16*)(ws + 2 * TC2 + 4 * CC2);
  bf16* vB = (bf16*)(ws + 3 * TC2 + 4 * CC2);
  char* p2 = ws + 4 * TC2 + 4 * CC2;
  float* qd = (float*)p2;        p2 += (size_t)T_DIM * K_LCP * 4;
  float* kd = (float*)p2;        p2 += (size_t)T_DIM * K_LCP * 4;
  float* vtsum = (float*)p2;     p2 += 32 * C_DIM * 4;
  float* vmean = (float*)p2;     p2 += C_DIM * 4;
  float* partial = (float*)p2;   p2 += 32 * C_DIM * 4;
  float* rowout = (float*)p2;    p2 += C_DIM * 4;
  int* tilemask = (int*)p2;      p2 += (T_DIM / 16) * 32 * 4;
  int* allmask = (int*)p2;       p2 += (T_DIM / 16) * 4;
  // contiguous flag block (zeroed as 112 ints by fused_a; 80 used)
  int* qneed = (int*)p2;         p2 += 16 * 4;
  int* kneed = (int*)p2;         p2 += 16 * 4;
  int* vneed = (int*)p2;         p2 += 16 * 4;
  int* pneed = (int*)p2;         p2 += 32 * 4;
  bf16* yb = xb;  // x (bf16) is dead after the QKV GEMM

  fused_a<<<1568, 256, 0, stream>>>(x, Wdq, Wdk, Wq, Wk, Wv, Wproj, xb, qd, kd,
                                    partial, qneed, wqt, wkt, wvt, wpt);
  fused_b<<<144, 256, 0, stream>>>(qd, kd, partial, Wv, tilemask, allmask,
                                   vmean, qneed, kneed, vneed, pneed);
  phase_c<<<400, 256, 0, stream>>>(xb, wqt, wkt, wvt, qB, kB, vB, vtsum, cosT,
                                   sinT, qneed, kneed, vneed, vmean, Wproj,
                                   rowout);
  attn2<<<dim3(T_DIM / QT, H_NUM), 256, 0, stream>>>(
      qB, kB, vB, qd, kd, vtsum, vmean, tilemask, allmask, pneed, yb);
  phase_e<<<512, 256, 0, stream>>>(yb, wpt, out, pneed, rowout, cosT, sinT);
}